// Round 4
// baseline (614.983 us; speedup 1.0000x reference)
//
#include <hip/hip_runtime.h>

#define N_TOK   8192
#define TOPK    2
#define N_EXP   8
#define DM      1024
#define DFF     2048
#define CAP     3072

typedef __attribute__((ext_vector_type(8))) short bf16x8;
typedef __attribute__((ext_vector_type(4))) float f32x4;

__device__ __forceinline__ unsigned short f2bf(float x) {
    union { float f; unsigned u; } un; un.f = x;
    unsigned r = un.u + 0x7fffu + ((un.u >> 16) & 1u);
    return (unsigned short)(r >> 16);
}
__device__ __forceinline__ float bf2f(unsigned short u) {
    union { unsigned u; float f; } c; c.u = ((unsigned)u) << 16; return c.f;
}

__device__ __forceinline__ void glds16(const void* g, void* l) {
    __builtin_amdgcn_global_load_lds(
        (const __attribute__((address_space(1))) unsigned int*)g,
        (__attribute__((address_space(3))) unsigned int*)l, 16, 0, 0);
}

// ---- x fp32 -> bf16 ----
__global__ void cvt_x_kernel(const float4* __restrict__ x, ushort4* __restrict__ xb) {
    int i = blockIdx.x * 256 + threadIdx.x;
    float4 v = x[i];
    ushort4 o;
    o.x = f2bf(v.x); o.y = f2bf(v.y); o.z = f2bf(v.z); o.w = f2bf(v.w);
    xb[i] = o;
}

// ---- transpose + convert, 64x64 tiles: in [E][R][C] fp32 -> out [E][C][R] bf16 ----
__global__ void transpose_cvt64_kernel(const float* __restrict__ inA, const float* __restrict__ inB,
                                       unsigned short* __restrict__ outA, unsigned short* __restrict__ outB,
                                       int R, int C) {
    __shared__ unsigned short L[64][72];
    const int z = blockIdx.z;
    const float* in = (z & 8) ? inB : inA;
    unsigned short* out = (z & 8) ? outB : outA;
    const int e = z & 7;
    const int r0 = blockIdx.y * 64, c0 = blockIdx.x * 64;
    const int t = threadIdx.x;
    const int rr = t >> 4;
    const int cv = t & 15;
    const float4* src = (const float4*)(in + ((size_t)e * R + r0) * C + c0);
    const int c4 = C >> 2;
#pragma unroll
    for (int i = 0; i < 4; i++) {
        int r = rr + 16 * i;
        float4 v = src[(size_t)r * c4 + cv];
        L[r][cv * 4 + 0] = f2bf(v.x);
        L[r][cv * 4 + 1] = f2bf(v.y);
        L[r][cv * 4 + 2] = f2bf(v.z);
        L[r][cv * 4 + 3] = f2bf(v.w);
    }
    __syncthreads();
    unsigned short* dst = out + ((size_t)e * C + c0) * R + r0;
    const int cc = t >> 4;
    const int rv = t & 15;
#pragma unroll
    for (int i = 0; i < 4; i++) {
        int c = cc + 16 * i;
        ushort4 o;
        o.x = L[rv * 4 + 0][c];
        o.y = L[rv * 4 + 1][c];
        o.z = L[rv * 4 + 2][c];
        o.w = L[rv * 4 + 3][c];
        *(ushort4*)(dst + (size_t)c * R + rv * 4) = o;
    }
}

// ---- dispatch: slot assignment per (token, k); also records inverse map ----
__global__ void dispatch_kernel(const int* __restrict__ eidx, const float* __restrict__ ewt,
                                int* __restrict__ counts, int* __restrict__ row_token,
                                float* __restrict__ row_weight, int* __restrict__ slot_of) {
    int i = blockIdx.x * 256 + threadIdx.x;
    if (i < N_TOK * TOPK) {
        int e = eidx[i];
        int pos = atomicAdd(&counts[e], 1);
        int slot = -1;
        if (pos < CAP) {
            slot = e * CAP + pos;
            row_token[slot] = i >> 1;   // TOPK == 2
            row_weight[slot] = ewt[i];
        }
        slot_of[i] = slot;
    }
}

// ===================================================================================
// GEMM1 — 256x(128+128) dual-output tile, BK=64, 8 waves, 128KB LDS double buffer.
// True m201-style 8-phase / 2-K-tile iteration:
//   - inline-asm ds_read_b128 (alias-invisible: compiler cannot inject vmcnt(0))
//   - explicit lgkmcnt(0)+sched_barrier(0) after BAR1 (rule #18)
//   - counted vmcnt only at 4 of 8 phase-ends: vmcnt(3)/none/vmcnt(2)/none (×2).
//     Never drains to 0 in the main loop; issue-to-wait >= 2.5 phases.
//   - balanced reads 8/4/8/4 per phase (B1 of tile t read one phase early, ph7/ph3)
//   - balanced staging 3/3/2/0 glds16 rounds per half-iter
// Ledger (per-thread rounds; K-tile = 8 rounds A0..A3,B1a,B1b,B2a,B2b):
//   ph0-end: out = t.B2(2) + (t+1).ph0(3) = 5 -> vmcnt(3) drains t.B2  -> ph1 reads B2
//   ph2-end: out = (t+1) all 8            -> vmcnt(2) drains first 6   -> ph3/4/6 reads
//   ph4-end: out = (t+1).B2(2)+(t+2).ph4(3)=5 -> vmcnt(3)              -> ph5 reads B2
//   ph6-end: out = (t+2) all 8            -> vmcnt(2)                  -> ph7/next-ph0
// LDS swizzle: chunk ^= (row&7), pre-swizzled global source + swizzled read (rule #21).
// ===================================================================================

#define DSRL(dst, ar, LIT) asm volatile("ds_read_b128 %0, %1 offset:" #LIT : "=&v"(dst) : "v"(ar))

#define RD_A0(B) do { \
    DSRL(aF[0][0], adA[B][0], 0);    DSRL(aF[0][1], adA[B][1], 0); \
    DSRL(aF[1][0], adA[B][0], 2048); DSRL(aF[1][1], adA[B][1], 2048); \
    DSRL(aF[2][0], adA[B][0], 4096); DSRL(aF[2][1], adA[B][1], 4096); \
    DSRL(aF[3][0], adA[B][0], 6144); DSRL(aF[3][1], adA[B][1], 6144); } while (0)

#define RD_A1(B) do { \
    DSRL(aF[0][0], adA[B][0], 8192);  DSRL(aF[0][1], adA[B][1], 8192); \
    DSRL(aF[1][0], adA[B][0], 10240); DSRL(aF[1][1], adA[B][1], 10240); \
    DSRL(aF[2][0], adA[B][0], 12288); DSRL(aF[2][1], adA[B][1], 12288); \
    DSRL(aF[3][0], adA[B][0], 14336); DSRL(aF[3][1], adA[B][1], 14336); } while (0)

#define RD_B1(B) do { \
    DSRL(b1F[0][0], adB[B][0], 32768); DSRL(b1F[0][1], adB[B][1], 32768); \
    DSRL(b1F[1][0], adB[B][0], 34816); DSRL(b1F[1][1], adB[B][1], 34816); } while (0)

#define RD_B2(B) do { \
    DSRL(b2F[0][0], adB[B][0], 49152); DSRL(b2F[0][1], adB[B][1], 49152); \
    DSRL(b2F[1][0], adB[B][0], 51200); DSRL(b2F[1][1], adB[B][1], 51200); } while (0)

#define MM(ACC, MH, BF) do { \
    _Pragma("unroll") for (int _mf = 0; _mf < 4; _mf++) \
    _Pragma("unroll") for (int _ff = 0; _ff < 2; _ff++) { \
        ACC[(MH)*4+_mf][_ff] = __builtin_amdgcn_mfma_f32_16x16x32_bf16(aF[_mf][0], BF[_ff][0], ACC[(MH)*4+_mf][_ff], 0, 0, 0); \
        ACC[(MH)*4+_mf][_ff] = __builtin_amdgcn_mfma_f32_16x16x32_bf16(aF[_mf][1], BF[_ff][1], ACC[(MH)*4+_mf][_ff], 0, 0, 0); \
    } } while (0)

#define ST_A3(bs)   do { glds16(xbc + offA[0], (bs)); glds16(xbc + offA[1], (bs) + 8192); glds16(xbc + offA[2], (bs) + 16384); } while (0)
#define ST_A1B1(bs) do { glds16(xbc + offA[3], (bs) + 24576); glds16(w1c + offB[0], (bs) + 32768); glds16(w1c + offB[1], (bs) + 40960); } while (0)
#define ST_B2A(bs)  do { glds16(w2c + offB[0], (bs) + 49152); glds16(w2c + offB[1], (bs) + 57344); \
    offA[0] += 128; offA[1] += 128; offA[2] += 128; offA[3] += 128; offB[0] += 128; offB[1] += 128; } while (0)

#define FENCE() asm volatile("" ::: "memory")
#define BARX() do { FENCE(); __builtin_amdgcn_s_barrier(); FENCE(); } while (0)
#define VMW(N) asm volatile("s_waitcnt vmcnt(" #N ")" ::: "memory")
#define NOST ((void)0)
#define NOWT ((void)0)

#define PH(RDS, STS, MMS, WT) do { \
    RDS; \
    STS; \
    BARX(); \
    asm volatile("s_waitcnt lgkmcnt(0)" ::: "memory"); \
    __builtin_amdgcn_sched_barrier(0); \
    __builtin_amdgcn_s_setprio(1); \
    MMS; \
    __builtin_amdgcn_s_setprio(0); \
    __builtin_amdgcn_sched_barrier(0); \
    WT; \
    BARX(); \
} while (0)

__global__ __launch_bounds__(512, 2)
void gemm1_kernel(const unsigned short* __restrict__ xb, const unsigned short* __restrict__ w1t,
                  const unsigned short* __restrict__ w2t, const int* __restrict__ counts,
                  const int* __restrict__ row_token, unsigned short* __restrict__ hidden) {
    // XCD-aware decode: xcd = bid&7 (hw round-robins XCD by blockIdx), r innermost
    // within an XCD's chunk -> B1/B2 panel (512KB) stays L2-resident across r-blocks.
    // With 192 = 16*12 blocks/XCD this makes e == xcd (one expert per XCD).
    const int bid = blockIdx.x;
    const int xcd = bid & 7;
    const int pos = bid >> 3;
    const int w = xcd * 192 + pos;          // 192 = (DFF/128)*(CAP/256)
    const int r0 = (w % 12) * 256;
    const int ef = w / 12;
    const int e = ef >> 4;
    const int f0 = (ef & 15) * 128;
    if (r0 >= counts[e]) return;

    extern __shared__ char smem[];   // 2 x { A 32KB | B1 16KB | B2 16KB } = 128KB

    const int t = threadIdx.x;
    const int lane = t & 63;
    const int wave = t >> 6;
    const int wm = wave >> 2;        // 0..1 : 128-row group
    const int wn = wave & 3;         // 0..3 : 32-f group

    // staging: linear LDS dest (t*16); source chunk pre-swizzled: c = pos ^ (row&7)
    const int csrc = (((t & 7) ^ ((t >> 3) & 7)) << 4);
    const int srow = t >> 3;

    const char* xbc = (const char*)xb;
    const char* w1c = (const char*)w1t;
    const char* w2c = (const char*)w2t;
    char* ldsT0 = smem + t * 16;
    char* ldsT1 = ldsT0 + 65536;

    unsigned offA[4];
#pragma unroll
    for (int i = 0; i < 4; i++) {
        int tok = row_token[e * CAP + r0 + i * 64 + srow];
        offA[i] = (unsigned)tok * (DM * 2) + csrc;
    }
    unsigned offB[2];
#pragma unroll
    for (int j = 0; j < 2; j++)
        offB[j] = (unsigned)(e * DFF + f0 + j * 64 + srow) * (DM * 2) + csrc;

    // ds_read addressing (32-bit LDS addr = low32 of generic pointer):
    const int l15 = lane & 15;
    const int lq = lane >> 4;
    const int swz = l15 & 7;
    const int cof0 = ((lq) ^ swz) << 4;
    const int cof1 = ((4 + lq) ^ swz) << 4;
    const unsigned ldsBase = (unsigned)(unsigned long long)smem;
    const unsigned aRow = ldsBase + (unsigned)((wm * 128 + l15) * 128);
    const unsigned bRow = ldsBase + (unsigned)((wn * 32 + l15) * 128);
    unsigned adA[2][2], adB[2][2];
    adA[0][0] = aRow + cof0;  adA[0][1] = aRow + cof1;
    adA[1][0] = adA[0][0] + 65536;  adA[1][1] = adA[0][1] + 65536;
    adB[0][0] = bRow + cof0;  adB[0][1] = bRow + cof1;
    adB[1][0] = adB[0][0] + 65536;  adB[1][1] = adB[0][1] + 65536;

    f32x4 accG[8][2], accV[8][2];
#pragma unroll
    for (int i = 0; i < 8; i++)
#pragma unroll
        for (int j = 0; j < 2; j++) {
            accG[i][j] = (f32x4){0.f, 0.f, 0.f, 0.f};
            accV[i][j] = (f32x4){0.f, 0.f, 0.f, 0.f};
        }

    bf16x8 aF[4][2], b1F[2][2], b2F[2][2];

    // ---- prologue: stage K-tile 0 into buf0 (8 rounds), publish first 6, read B1(t0)
    ST_A3(ldsT0); ST_A1B1(ldsT0); ST_B2A(ldsT0);
    VMW(2);
    BARX();
    RD_B1(0);

    // ---- main loop: 7 iters x 2 K-tiles (t=0..13); tail covers 14,15
#pragma unroll 1
    for (int it = 0; it < 7; ++it) {
        PH(RD_A0(0), ST_A3(ldsT1),   MM(accG, 0, b1F), VMW(3));
        PH(RD_B2(0), ST_A1B1(ldsT1), MM(accV, 0, b2F), NOWT);
        PH(RD_A1(0), ST_B2A(ldsT1),  MM(accG, 1, b1F), VMW(2));
        PH(RD_B1(1), NOST,           MM(accV, 1, b2F), NOWT);
        PH(RD_A0(1), ST_A3(ldsT0),   MM(accG, 0, b1F), VMW(3));
        PH(RD_B2(1), ST_A1B1(ldsT0), MM(accV, 0, b2F), NOWT);
        PH(RD_A1(1), ST_B2A(ldsT0),  MM(accG, 1, b1F), VMW(2));
        PH(RD_B1(0), NOST,           MM(accV, 1, b2F), NOWT);
    }
    // ---- tail: t=14 (buf0), t=15 (buf1); stage only 15; drain in ph4
    PH(RD_A0(0), ST_A3(ldsT1),   MM(accG, 0, b1F), VMW(3));
    PH(RD_B2(0), ST_A1B1(ldsT1), MM(accV, 0, b2F), NOWT);
    PH(RD_A1(0), ST_B2A(ldsT1),  MM(accG, 1, b1F), VMW(2));
    PH(RD_B1(1), NOST,           MM(accV, 1, b2F), NOWT);
    PH(RD_A0(1), NOST,           MM(accG, 0, b1F), VMW(0));
    PH(RD_B2(1), NOST,           MM(accV, 0, b2F), NOWT);
    PH(RD_A1(1), NOST,           MM(accG, 1, b1F), NOWT);
    asm volatile("s_waitcnt lgkmcnt(0)" ::: "memory");
    __builtin_amdgcn_sched_barrier(0);
    MM(accV, 1, b2F);

    // ---- silu(g)*v epilogue -> hidden bf16
    const size_t hbase = ((size_t)e * CAP + r0) * DFF + f0;
    const int mBase = wm * 128;
    const int nBase = wn * 32;
#pragma unroll
    for (int mf = 0; mf < 8; mf++)
#pragma unroll
        for (int ff = 0; ff < 2; ff++)
#pragma unroll
            for (int r = 0; r < 4; r++) {
                int m = mBase + mf * 16 + lq * 4 + r;
                int n = nBase + ff * 16 + l15;
                float g = accG[mf][ff][r];
                float v = accV[mf][ff][r];
                float h = (g / (1.f + __expf(-g))) * v;
                hidden[hbase + (size_t)m * DFF + n] = f2bf(h);
            }
}

// ---- GEMM2: out_rows[slot] = (hidden @ w3^T) * row_weight, bf16, no atomics ----
__global__ __launch_bounds__(256, 3)
void gemm2_kernel(const unsigned short* __restrict__ hidden, const unsigned short* __restrict__ w3t,
                  const int* __restrict__ counts, const float* __restrict__ row_weight,
                  unsigned short* __restrict__ out_rows) {
    const int e = blockIdx.z;
    const int r0 = blockIdx.y * 128;
    if (r0 >= counts[e]) return;
    const int d0 = blockIdx.x * 128;

    __shared__ unsigned short lA[128 * 32];
    __shared__ unsigned short lB[128 * 32];

    const int t = threadIdx.x;
    const int lane = t & 63;
    const int wave = t >> 6;

    const int rstage = t >> 2;
    const int cs = (t & 3) ^ ((rstage >> 1) & 3);
    const int kbyte = cs * 16;

    const char* pA0 = (const char*)(hidden + ((size_t)e * CAP + r0 + rstage) * DFF) + kbyte;
    const char* pA1 = pA0 + (size_t)64 * DFF * 2;
    const char* pB0 = (const char*)(w3t + ((size_t)e * DM + d0 + rstage) * DFF) + kbyte;
    const char* pB1 = pB0 + (size_t)64 * DFF * 2;

    char* lAp = (char*)lA + t * 16;
    char* lBp = (char*)lB + t * 16;

    const int mw = (wave & 1) * 64;
    const int nw = (wave >> 1) * 64;
    const int l15 = lane & 15;
    const int lq = lane >> 4;
    const int swz = (l15 >> 1) & 3;
    const unsigned short* aBase = lA + (mw + l15) * 32 + ((lq ^ swz) * 8);
    const unsigned short* bBase = lB + (nw + l15) * 32 + ((lq ^ swz) * 8);

    f32x4 acc[4][4];
#pragma unroll
    for (int i = 0; i < 4; i++)
#pragma unroll
        for (int j = 0; j < 4; j++) acc[i][j] = (f32x4){0.f, 0.f, 0.f, 0.f};

    for (int k0 = 0; k0 < DFF; k0 += 32) {
        glds16(pA0, lAp);  glds16(pA1, lAp + 4096);
        glds16(pB0, lBp);  glds16(pB1, lBp + 4096);
        pA0 += 64; pA1 += 64; pB0 += 64; pB1 += 64;
        __syncthreads();

        bf16x8 a[4], b[4];
#pragma unroll
        for (int i = 0; i < 4; i++) {
            a[i] = *(const bf16x8*)(aBase + i * 512);
            b[i] = *(const bf16x8*)(bBase + i * 512);
        }
#pragma unroll
        for (int i = 0; i < 4; i++)
#pragma unroll
            for (int j = 0; j < 4; j++)
                acc[i][j] = __builtin_amdgcn_mfma_f32_16x16x32_bf16(a[i], b[j], acc[i][j], 0, 0, 0);
        __syncthreads();
    }

    const float* rw = row_weight + e * CAP + r0;
#pragma unroll
    for (int i = 0; i < 4; i++)
#pragma unroll
        for (int r = 0; r < 4; r++) {
            int m = mw + i * 16 + lq * 4 + r;
            float w = rw[m];   // 0 for padding rows (memset) -> writes 0
            unsigned short* orow = out_rows + ((size_t)(e * CAP + r0 + m)) * DM + d0 + nw + l15;
#pragma unroll
            for (int j = 0; j < 4; j++)
                orow[j * 16] = f2bf(acc[i][j][r] * w);
        }
}

// ---- combine: out[tok] = out_rows[slot0] + out_rows[slot1] (pre-weighted) ----
__global__ void combine_kernel(const int* __restrict__ slot_of,
                               const unsigned short* __restrict__ out_rows,
                               float4* __restrict__ out) {
    const int tok = blockIdx.x;
    const int t = threadIdx.x;
    const int s0 = slot_of[2 * tok];
    const int s1 = slot_of[2 * tok + 1];
    float4 acc = {0.f, 0.f, 0.f, 0.f};
    if (s0 >= 0) {
        ushort4 r = ((const ushort4*)(out_rows + (size_t)s0 * DM))[t];
        acc.x += bf2f(r.x); acc.y += bf2f(r.y); acc.z += bf2f(r.z); acc.w += bf2f(r.w);
    }
    if (s1 >= 0) {
        ushort4 r = ((const ushort4*)(out_rows + (size_t)s1 * DM))[t];
        acc.x += bf2f(r.x); acc.y += bf2f(r.y); acc.z += bf2f(r.z); acc.w += bf2f(r.w);
    }
    out[(size_t)tok * (DM / 4) + t] = acc;
}

extern "C" void kernel_launch(void* const* d_in, const int* in_sizes, int n_in,
                              void* d_out, int out_size, void* d_ws, size_t ws_size,
                              hipStream_t stream) {
    const float* x = (const float*)d_in[0];
    const int* eidx = (const int*)d_in[1];
    const float* ewt = (const float*)d_in[2];
    const float* w1 = (const float*)d_in[3];
    const float* w2 = (const float*)d_in[4];
    const float* w3 = (const float*)d_in[5];
    float* out = (float*)d_out;

    char* ws = (char*)d_ws;
    size_t off = 0;
    auto alloc = [&](size_t b) { size_t o = off; off += (b + 255) & ~(size_t)255; return o; };
    int*   counts     = (int*)(ws + alloc(N_EXP * 4));
    int*   row_token  = (int*)(ws + alloc((size_t)N_EXP * CAP * 4));
    float* row_weight = (float*)(ws + alloc((size_t)N_EXP * CAP * 4));
    size_t hdr_end = off;  // memset range: counts + row_token + row_weight
    int*   slot_of    = (int*)(ws + alloc((size_t)N_TOK * TOPK * 4));  // fully written by dispatch
    unsigned short* xb  = (unsigned short*)(ws + alloc((size_t)N_TOK * DM * 2));
    unsigned short* w1t = (unsigned short*)(ws + alloc((size_t)N_EXP * DFF * DM * 2));
    unsigned short* w2t = (unsigned short*)(ws + alloc((size_t)N_EXP * DFF * DM * 2));
    unsigned short* w3t = (unsigned short*)(ws + alloc((size_t)N_EXP * DM * DFF * 2));
    unsigned short* hidden = (unsigned short*)(ws + alloc((size_t)N_EXP * CAP * DFF * 2));
    // out_rows (48 MB) aliases w1t+w2t (64 MB) — both dead after gemm1 completes.
    unsigned short* out_rows = w1t;
    (void)ws_size; (void)in_sizes; (void)n_in;

    static bool attr_done = false;
    if (!attr_done) {
        hipFuncSetAttribute((const void*)gemm1_kernel,
                            hipFuncAttributeMaxDynamicSharedMemorySize, 131072);
        attr_done = true;
    }

    hipMemsetAsync(ws, 0, hdr_end, stream);  // counts + row_token + row_weight

    cvt_x_kernel<<<(N_TOK * DM / 4) / 256, 256, 0, stream>>>((const float4*)x, (ushort4*)xb);
    transpose_cvt64_kernel<<<dim3(DFF / 64, DM / 64, 16), 256, 0, stream>>>(w1, w2, w1t, w2t, DM, DFF);
    transpose_cvt64_kernel<<<dim3(DM / 64, DFF / 64, 8), 256, 0, stream>>>(w3, w3, w3t, w3t, DFF, DM);
    dispatch_kernel<<<(N_TOK * TOPK) / 256, 256, 0, stream>>>(eidx, ewt, counts, row_token, row_weight, slot_of);

    gemm1_kernel<<<dim3((DFF / 128) * (CAP / 256) * N_EXP), 512, 131072, stream>>>(xb, w1t, w2t, counts, row_token, hidden);
    gemm2_kernel<<<dim3(DM / 128, CAP / 128, N_EXP), 256, 0, stream>>>(hidden, w3t, counts, row_weight, out_rows);
    combine_kernel<<<N_TOK, 256, 0, stream>>>(slot_of, out_rows, (float4*)out);
}